// Round 12
// baseline (233.987 us; speedup 1.0000x reference)
//
#include <hip/hip_runtime.h>
#include <hip/hip_fp16.h>

#define D_NODE 64
#define H_DIM  128
#define REC_H  192   // halves per node record: 64 (e16) + 128 (P) = 384 B

struct Half8 { __half2 h[4]; };

typedef _Float16 h2v __attribute__((ext_vector_type(2)));
struct H2x4 { h2v h[4]; };   // 16 B = 8 halves

#if defined(__has_builtin)
#  if __has_builtin(__builtin_amdgcn_fdot2)
#    define HAVE_FDOT2 1
#  endif
#endif

// ---------------------------------------------------------------------------
// Fused prep kernel:
//   blocks [0, pS+pA): stage emb rows -> f16 records + P via dot2.
//   blocks [pS+pA, ...): zero segsum and per-node histogram.
// ---------------------------------------------------------------------------
__global__ void __launch_bounds__(256)
prep_kernel(const float* __restrict__ emb_s,
            const float* __restrict__ emb_a,
            const float* __restrict__ W1,
            const float* __restrict__ b1,
            __half* __restrict__ recS,
            __half* __restrict__ recA,
            float* __restrict__ segsum,
            unsigned* __restrict__ hist,
            int numS, int numA, int pS, int pA)
{
    const int tid = threadIdx.x;
    int b = blockIdx.x;

    if (b >= pS + pA) {                       // ---- role: zero segsum + hist ----
        const int i = (b - pS - pA) * 256 + tid;
        if (i < numS) { segsum[i] = 0.0f; hist[i] = 0u; }
        return;
    }

    const bool isS = (b < pS);
    const int pb = isS ? b : b - pS;
    const float* etab = isS ? emb_s : emb_a;
    __half* rec = isS ? recS : recA;
    const int rowsTot = isS ? numS : numA;
    const int rowBase = pb * 64;

    __shared__ __half eT[64 * D_NODE];        // 8 KB (f16 rows)

    // ---- stage 64 rows: global f32 -> f16 -> LDS + e16 record write ----
    {
        const float4* src4 = (const float4*)(etab + (size_t)rowBase * D_NODE);
#pragma unroll
        for (int it = 0; it < 2; ++it) {
            const int c = tid + it * 256;     // chunk of 8 halves; 512 total
            const int row = c >> 3;           // 0..63
            const int sub = c & 7;
            const bool ok = (rowBase + row < rowsTot);
            float4 a = make_float4(0.f, 0.f, 0.f, 0.f), d = a;
            if (ok) { a = src4[2 * c]; d = src4[2 * c + 1]; }
            Half8 o;
            o.h[0] = __floats2half2_rn(a.x, a.y);
            o.h[1] = __floats2half2_rn(a.z, a.w);
            o.h[2] = __floats2half2_rn(d.x, d.y);
            o.h[3] = __floats2half2_rn(d.z, d.w);
            ((Half8*)eT)[c] = o;
            if (ok)
                ((Half8*)(rec + (size_t)(rowBase + row) * REC_H))[sub] = o;
        }
    }

    // ---- W column (f16 pairs) in registers ----
    const int col = tid & 127;
    const int rhalf = tid >> 7;               // 0/1: which 32-row half
    const float* Wh = isS ? W1 : (W1 + D_NODE * H_DIM);
    h2v w2[32];
#pragma unroll
    for (int k = 0; k < 32; ++k) {
        w2[k][0] = (_Float16)Wh[(2 * k) * H_DIM + col];
        w2[k][1] = (_Float16)Wh[(2 * k + 1) * H_DIM + col];
    }
    const float bias = isS ? b1[col] : 0.0f;

    __syncthreads();

    // ---- ILP-4 over 32 rows; b128 LDS reads, dot2 into f32 ----
    for (int r0 = rhalf * 32; r0 < rhalf * 32 + 32; r0 += 4) {
        const H2x4* e0 = (const H2x4*)&eT[(r0 + 0) * D_NODE];
        const H2x4* e1 = (const H2x4*)&eT[(r0 + 1) * D_NODE];
        const H2x4* e2 = (const H2x4*)&eT[(r0 + 2) * D_NODE];
        const H2x4* e3 = (const H2x4*)&eT[(r0 + 3) * D_NODE];
        float a0 = bias, a1 = bias, a2 = bias, a3 = bias;
#pragma unroll
        for (int k8 = 0; k8 < D_NODE / 8; ++k8) {      // 8 iters
            const H2x4 v0 = e0[k8];
            const H2x4 v1 = e1[k8];
            const H2x4 v2 = e2[k8];
            const H2x4 v3 = e3[k8];
#pragma unroll
            for (int j = 0; j < 4; ++j) {
                const h2v w = w2[4 * k8 + j];
#ifdef HAVE_FDOT2
                a0 = __builtin_amdgcn_fdot2(v0.h[j], w, a0, false);
                a1 = __builtin_amdgcn_fdot2(v1.h[j], w, a1, false);
                a2 = __builtin_amdgcn_fdot2(v2.h[j], w, a2, false);
                a3 = __builtin_amdgcn_fdot2(v3.h[j], w, a3, false);
#else
                const float wx = (float)w[0], wy = (float)w[1];
                a0 = fmaf((float)v0.h[j][0], wx, a0); a0 = fmaf((float)v0.h[j][1], wy, a0);
                a1 = fmaf((float)v1.h[j][0], wx, a1); a1 = fmaf((float)v1.h[j][1], wy, a1);
                a2 = fmaf((float)v2.h[j][0], wx, a2); a2 = fmaf((float)v2.h[j][1], wy, a2);
                a3 = fmaf((float)v3.h[j][0], wx, a3); a3 = fmaf((float)v3.h[j][1], wy, a3);
#endif
            }
        }
        const int row = rowBase + r0;
        if (row + 0 < rowsTot)
            rec[(size_t)(row + 0) * REC_H + D_NODE + col] = __float2half(a0);
        if (row + 1 < rowsTot)
            rec[(size_t)(row + 1) * REC_H + D_NODE + col] = __float2half(a1);
        if (row + 2 < rowsTot)
            rec[(size_t)(row + 2) * REC_H + D_NODE + col] = __float2half(a2);
        if (row + 3 < rowsTot)
            rec[(size_t)(row + 3) * REC_H + D_NODE + col] = __float2half(a3);
    }
}

// ---------------------------------------------------------------------------
// Per-node histogram: hist[s] += 1 (global atomics; ~E/numS = 20 per bin).
// ---------------------------------------------------------------------------
__global__ void __launch_bounds__(256)
hist_kernel(const int* __restrict__ idx,
            unsigned* __restrict__ hist,
            int E)
{
    const int e = blockIdx.x * 256 + (int)threadIdx.x;
    if (e < E) atomicAdd(&hist[idx[e]], 1u);
}

// ---------------------------------------------------------------------------
// Hierarchical exclusive scan over numS entries (numS <= 65536).
//   scan1: per-256-block exclusive scan -> cursor; block sums -> bsum
//   scan2: single-block exclusive scan of bsum in place
//   scan3: cursor[i] += bsum[block]
// ---------------------------------------------------------------------------
__global__ void __launch_bounds__(256)
scan1_kernel(const unsigned* __restrict__ hist,
             unsigned* __restrict__ cursor,
             unsigned* __restrict__ bsum,
             int n)
{
    __shared__ unsigned buf[2][256];
    const int tid = threadIdx.x;
    const int g = blockIdx.x * 256 + tid;
    const unsigned v = (g < n) ? hist[g] : 0u;
    buf[0][tid] = v;
    __syncthreads();
    int src = 0;
#pragma unroll
    for (int off = 1; off < 256; off <<= 1) {
        unsigned x = buf[src][tid];
        if (tid >= off) x += buf[src][tid - off];
        buf[src ^ 1][tid] = x;
        src ^= 1;
        __syncthreads();
    }
    const unsigned incl = buf[src][tid];
    if (g < n) cursor[g] = incl - v;
    if (tid == 255) bsum[blockIdx.x] = incl;
}

__global__ void __launch_bounds__(256)
scan2_kernel(unsigned* __restrict__ bsum, int nb)
{
    __shared__ unsigned buf[2][256];
    const int tid = threadIdx.x;
    const unsigned v = (tid < nb) ? bsum[tid] : 0u;
    buf[0][tid] = v;
    __syncthreads();
    int src = 0;
#pragma unroll
    for (int off = 1; off < 256; off <<= 1) {
        unsigned x = buf[src][tid];
        if (tid >= off) x += buf[src][tid - off];
        buf[src ^ 1][tid] = x;
        src ^= 1;
        __syncthreads();
    }
    if (tid < nb) bsum[tid] = buf[src][tid] - v;   // exclusive
}

__global__ void __launch_bounds__(256)
scan3_kernel(unsigned* __restrict__ cursor,
             const unsigned* __restrict__ bsum,
             int n)
{
    const int g = blockIdx.x * 256 + (int)threadIdx.x;
    if (g < n) cursor[g] += bsum[blockIdx.x];
}

// ---------------------------------------------------------------------------
// Scatter edges into exact s-sorted (CSR) order: sorted[pos] = {s, a, e, 0}.
// ~20 atomics per cursor address -> low contention.
// ---------------------------------------------------------------------------
__global__ void __launch_bounds__(256)
scatter_kernel(const int* __restrict__ idx,
               unsigned* __restrict__ cursor,
               int4* __restrict__ sorted,
               int E)
{
    const int e = blockIdx.x * 256 + (int)threadIdx.x;
    if (e >= E) return;
    const int s = idx[e];
    const int a = idx[E + e];
    const unsigned pos = atomicAdd(&cursor[s], 1u);
    sorted[pos] = make_int4(s, a, e, 0);
}

// ---------------------------------------------------------------------------
// Main edge pass (run-sharing): each 8-lane group processes 16 CONSECUTIVE
// sorted edges sequentially. s-record is held in registers across a same-s
// run (group-uniform reload on change); a-records prefetched 4 edges ahead.
// segsum accumulated per run, one atomicAdd per flush.
// ---------------------------------------------------------------------------
__global__ void __launch_bounds__(256)
edge_main_kernel(const __half* __restrict__ recS,
                 const __half* __restrict__ recA,
                 const int4* __restrict__ sorted,
                 const float* __restrict__ W2,
                 const float* __restrict__ b2,
                 const float* __restrict__ logT,
                 float* __restrict__ out_costs,
                 float* __restrict__ segsum,
                 int E)
{
    const int gid = blockIdx.x * 256 + (int)threadIdx.x;
    const int grp = gid >> 3;
    const int t = gid & 7;
    const int base = grp * 16;
    if (base >= E) return;
    const int nEdge = (E - base < 16) ? (E - base) : 16;

    // my 2 sorted entries (edges base+t and base+8+t), clamped for tails
    const int i0 = (base + t < E) ? (base + t) : (E - 1);
    const int i1 = (base + 8 + t < E) ? (base + 8 + t) : (E - 1);
    const int4 q0 = sorted[i0];
    const int4 q1 = sorted[i1];

    // W2 chunks t and t+8 (dims [8t,8t+8) and [8(t+8),8(t+8)+8))
    const float4* w4 = (const float4*)W2;
    const float4 wl0 = w4[2 * t], wl1 = w4[2 * t + 1];
    const float4 wh0 = w4[2 * (t + 8)], wh1 = w4[2 * (t + 8) + 1];
    const float bb = b2[0];
    const float invT = __expf(-logT[0]);    // 1/temp

    int sCur = -1;
    uint4 S0, S1, S2;
    float accE = 0.0f;

#define NORM_ACC(XS, XA, NACC)                                             \
    {                                                                      \
        const __half2* hs = (const __half2*)&XS;                           \
        const __half2* ha = (const __half2*)&XA;                           \
        _Pragma("unroll")                                                  \
        for (int k = 0; k < 4; ++k) {                                      \
            float2 fs = __half22float2(hs[k]);                             \
            float2 fa = __half22float2(ha[k]);                             \
            float d0 = fs.x - fa.x, d1 = fs.y - fa.y;                      \
            NACC = fmaf(d0, d0, NACC);                                     \
            NACC = fmaf(d1, d1, NACC);                                     \
        }                                                                  \
    }

#define GATE_ACC(PS, PA, W0, W1, G)                                        \
    {                                                                      \
        const __half2* hp = (const __half2*)&PS;                           \
        const __half2* hq = (const __half2*)&PA;                           \
        const float wv[8] = {W0.x, W0.y, W0.z, W0.w,                       \
                             W1.x, W1.y, W1.z, W1.w};                      \
        _Pragma("unroll")                                                  \
        for (int k = 0; k < 4; ++k) {                                      \
            float2 fp = __half22float2(hp[k]);                             \
            float2 fq = __half22float2(hq[k]);                             \
            float h0 = fmaxf(fp.x + fq.x, 0.0f);                           \
            float h1 = fmaxf(fp.y + fq.y, 0.0f);                           \
            G = fmaf(h0, wv[2 * k], G);                                    \
            G = fmaf(h1, wv[2 * k + 1], G);                                \
        }                                                                  \
    }

    for (int c = 0; c < 16; c += 4) {
        // meta (group-uniform via shfl) + prefetch 4 a-records
        int sj0, sj1, sj2, sj3, aj, oj0, oj1, oj2, oj3;
        uint4 A00, A01, A02, A10, A11, A12, A20, A21, A22, A30, A31, A32;
        {
            const int4 qa = (c < 8) ? q0 : q1;   // c in {0,4,8,12}; j=c+k
            // k = 0..3 -> j = c..c+3; src lane = j & 7; reg = j>>3 handled by qa
            // (c=4 block spans j=4..7, still q0; c=12 -> q1)
            sj0 = __shfl(qa.x, (c + 0) & 7, 8);
            aj  = __shfl(qa.y, (c + 0) & 7, 8);
            oj0 = __shfl(qa.z, (c + 0) & 7, 8);
            { const uint4* ra = (const uint4*)(recA + (size_t)aj * REC_H);
              A00 = ra[t]; A01 = ra[8 + t]; A02 = ra[16 + t]; }
            sj1 = __shfl(qa.x, (c + 1) & 7, 8);
            aj  = __shfl(qa.y, (c + 1) & 7, 8);
            oj1 = __shfl(qa.z, (c + 1) & 7, 8);
            { const uint4* ra = (const uint4*)(recA + (size_t)aj * REC_H);
              A10 = ra[t]; A11 = ra[8 + t]; A12 = ra[16 + t]; }
            sj2 = __shfl(qa.x, (c + 2) & 7, 8);
            aj  = __shfl(qa.y, (c + 2) & 7, 8);
            oj2 = __shfl(qa.z, (c + 2) & 7, 8);
            { const uint4* ra = (const uint4*)(recA + (size_t)aj * REC_H);
              A20 = ra[t]; A21 = ra[8 + t]; A22 = ra[16 + t]; }
            sj3 = __shfl(qa.x, (c + 3) & 7, 8);
            aj  = __shfl(qa.y, (c + 3) & 7, 8);
            oj3 = __shfl(qa.z, (c + 3) & 7, 8);
            { const uint4* ra = (const uint4*)(recA + (size_t)aj * REC_H);
              A30 = ra[t]; A31 = ra[8 + t]; A32 = ra[16 + t]; }
        }

#define PROC_EDGE(SJ, OJ, B0, B1, B2, JIDX)                                \
        {                                                                  \
            if (SJ != sCur) {                                              \
                if (t == 0 && sCur >= 0) atomicAdd(&segsum[sCur], accE);   \
                accE = 0.0f;                                               \
                const uint4* rs = (const uint4*)(recS + (size_t)SJ * REC_H);\
                S0 = rs[t]; S1 = rs[8 + t]; S2 = rs[16 + t];               \
                sCur = SJ;                                                 \
            }                                                              \
            float n = 0.0f, g = 0.0f;                                      \
            NORM_ACC(S0, B0, n)                                            \
            GATE_ACC(S1, B1, wl0, wl1, g)                                  \
            GATE_ACC(S2, B2, wh0, wh1, g)                                  \
            n += __shfl_xor(n, 1); g += __shfl_xor(g, 1);                  \
            n += __shfl_xor(n, 2); g += __shfl_xor(g, 2);                  \
            n += __shfl_xor(n, 4); g += __shfl_xor(g, 4);                  \
            if (t == 0 && (JIDX) < nEdge) {                                \
                const float gate = 1.0f / (1.0f + __expf(-(g + bb)));      \
                const float cost = sqrtf(n) * gate;                        \
                out_costs[OJ] = cost;                                      \
                accE += __expf(-cost * invT);                              \
            }                                                              \
        }

        PROC_EDGE(sj0, oj0, A00, A01, A02, c + 0)
        PROC_EDGE(sj1, oj1, A10, A11, A12, c + 1)
        PROC_EDGE(sj2, oj2, A20, A21, A22, c + 2)
        PROC_EDGE(sj3, oj3, A30, A31, A32, c + 3)
#undef PROC_EDGE
    }

    if (t == 0 && sCur >= 0) atomicAdd(&segsum[sCur], accE);
#undef NORM_ACC
#undef GATE_ACC
}

// ---------------------------------------------------------------------------
// edge_weights = exp(-cost/temp) / segsum[s]  (original edge order)
// ---------------------------------------------------------------------------
__global__ void __launch_bounds__(256)
edge_norm_kernel(const int* __restrict__ idx,
                 const float* __restrict__ out_costs,
                 const float* __restrict__ segsum,
                 const float* __restrict__ logT,
                 float* __restrict__ out_w,
                 int E)
{
    const int e = blockIdx.x * blockDim.x + threadIdx.x;
    if (e >= E) return;
    const int s = idx[e];
    const float invT = __expf(-logT[0]);
    const float ex = __expf(-out_costs[e] * invT);
    out_w[e] = ex / segsum[s];
}

// ---------------------------------------------------------------------------
extern "C" void kernel_launch(void* const* d_in, const int* in_sizes, int n_in,
                              void* d_out, int out_size, void* d_ws, size_t ws_size,
                              hipStream_t stream)
{
    const float* emb_s = (const float*)d_in[0];
    const float* emb_a = (const float*)d_in[1];
    const int*   idx   = (const int*)d_in[2];
    const float* W1    = (const float*)d_in[3];
    const float* b1    = (const float*)d_in[4];
    const float* W2    = (const float*)d_in[5];
    const float* b2    = (const float*)d_in[6];
    const float* logT  = (const float*)d_in[7];

    const int numS = in_sizes[0] / D_NODE;
    const int numA = in_sizes[1] / D_NODE;
    const int E    = in_sizes[2] / 2;

    float* out = (float*)d_out;            // [0,E) weights, [E,2E) costs

    // workspace layout
    char* ws = (char*)d_ws;
    __half*   recS   = (__half*)ws;    ws += (size_t)numS * REC_H * sizeof(__half);
    __half*   recA   = (__half*)ws;    ws += (size_t)numA * REC_H * sizeof(__half);
    int4*     sorted = (int4*)ws;      ws += (size_t)E * sizeof(int4);
    float*    segsum = (float*)ws;     ws += (size_t)numS * sizeof(float);
    unsigned* hist   = (unsigned*)ws;  ws += (size_t)numS * sizeof(unsigned);
    unsigned* cursor = (unsigned*)ws;  ws += (size_t)numS * sizeof(unsigned);
    unsigned* bsum   = (unsigned*)ws;

    const int nScanB = (numS + 255) / 256;   // <= 256 required (numS <= 65536)

    // fused prep: convert + P(f16) + zero segsum/hist
    const int pS = (numS + 63) / 64;
    const int pA = (numA + 63) / 64;
    const int zB = (numS + 255) / 256;
    prep_kernel<<<pS + pA + zB, 256, 0, stream>>>(emb_s, emb_a, W1, b1,
                                                  recS, recA, segsum, hist,
                                                  numS, numA, pS, pA);

    // exact sort by source node (CSR order)
    hist_kernel<<<(E + 255) / 256, 256, 0, stream>>>(idx, hist, E);
    scan1_kernel<<<nScanB, 256, 0, stream>>>(hist, cursor, bsum, numS);
    scan2_kernel<<<1, 256, 0, stream>>>(bsum, nScanB);
    scan3_kernel<<<nScanB, 256, 0, stream>>>(cursor, bsum, numS);
    scatter_kernel<<<(E + 255) / 256, 256, 0, stream>>>(idx, cursor, sorted, E);

    // main edge pass: 8-lane groups, 16 consecutive sorted edges each
    {
        const int groups = (E + 15) / 16;
        const long long threads = (long long)groups * 8;
        const int blocks = (int)((threads + 255) / 256);
        edge_main_kernel<<<blocks, 256, 0, stream>>>(recS, recA, sorted, W2, b2,
                                                     logT, out + E, segsum, E);
    }

    edge_norm_kernel<<<(E + 255) / 256, 256, 0, stream>>>(idx, out + E, segsum,
                                                          logT, out, E);
}

// Round 14
// 142.552 us; speedup vs baseline: 1.6414x; 1.6414x over previous
//
#include <hip/hip_runtime.h>
#include <hip/hip_fp16.h>

#define D_NODE 64
#define H_DIM  128
#define REC_H  192   // halves per node record: 64 (e16) + 128 (P) = 384 B

struct Half8 { __half2 h[4]; };

typedef _Float16 h2v __attribute__((ext_vector_type(2)));
struct H2x4 { h2v h[4]; };   // 16 B = 8 halves

#if defined(__has_builtin)
#  if __has_builtin(__builtin_amdgcn_fdot2)
#    define HAVE_FDOT2 1
#  endif
#endif

__device__ inline float dot2acc(h2v a, h2v b, float c)
{
#ifdef HAVE_FDOT2
    return __builtin_amdgcn_fdot2(a, b, c, false);
#else
    return fmaf((float)a[0], (float)b[0], fmaf((float)a[1], (float)b[1], c));
#endif
}

// element-wise relu on a packed half2 (compiler fuses to v_pk_max_f16)
__device__ inline __half2 relu2(__half2 a)
{
    const __half z = __float2half(0.0f);
    __half2 r;
    r.x = __hmax(a.x, z);
    r.y = __hmax(a.y, z);
    return r;
}

// ---------------------------------------------------------------------------
// Fused prep kernel:
//   blocks [0, pS+pA): per-block 64 node rows —
//     stage emb rows -> f16 (LDS + e16 record region write),
//     P = emb @ W1_half (+b1 for S): 2 COLS PER THREAD (64 col-threads x
//     4 row-quarters) so each b128 LDS read feeds two fdot2 -> halved
//     ds_read count vs 1-col scheme.
//   blocks [pS+pA, ...): zero segsum.
// ---------------------------------------------------------------------------
__global__ void __launch_bounds__(256)
prep_kernel(const float* __restrict__ emb_s,
            const float* __restrict__ emb_a,
            const float* __restrict__ W1,
            const float* __restrict__ b1,
            __half* __restrict__ recS,
            __half* __restrict__ recA,
            float* __restrict__ segsum,
            int numS, int numA, int pS, int pA)
{
    const int tid = threadIdx.x;
    int b = blockIdx.x;

    if (b >= pS + pA) {                       // ---- role: zero segsum ----
        const int i = (b - pS - pA) * 256 + tid;
        if (i < numS) segsum[i] = 0.0f;
        return;
    }

    const bool isS = (b < pS);
    const int pb = isS ? b : b - pS;
    const float* etab = isS ? emb_s : emb_a;
    __half* rec = isS ? recS : recA;
    const int rowsTot = isS ? numS : numA;
    const int rowBase = pb * 64;

    __shared__ __half eT[64 * D_NODE];        // 8 KB (f16 rows)

    // ---- stage 64 rows: global f32 -> f16 -> LDS + e16 record write ----
    {
        const float4* src4 = (const float4*)(etab + (size_t)rowBase * D_NODE);
#pragma unroll
        for (int it = 0; it < 2; ++it) {
            const int c = tid + it * 256;     // chunk of 8 halves; 512 total
            const int row = c >> 3;           // 0..63
            const int sub = c & 7;
            const bool ok = (rowBase + row < rowsTot);
            float4 a = make_float4(0.f, 0.f, 0.f, 0.f), d = a;
            if (ok) { a = src4[2 * c]; d = src4[2 * c + 1]; }
            Half8 o;
            o.h[0] = __floats2half2_rn(a.x, a.y);
            o.h[1] = __floats2half2_rn(a.z, a.w);
            o.h[2] = __floats2half2_rn(d.x, d.y);
            o.h[3] = __floats2half2_rn(d.z, d.w);
            ((Half8*)eT)[c] = o;
            if (ok)
                ((Half8*)(rec + (size_t)(rowBase + row) * REC_H))[sub] = o;
        }
    }

    // ---- W columns col2 and col2+64 (f16 pairs) in registers ----
    const int col2 = tid & 63;                // 0..63
    const int rq   = tid >> 6;                // 0..3: which 16-row quarter
    const float* Wh = isS ? W1 : (W1 + D_NODE * H_DIM);
    h2v wA[32], wB[32];
#pragma unroll
    for (int k = 0; k < 32; ++k) {
        wA[k][0] = (_Float16)Wh[(2 * k) * H_DIM + col2];
        wA[k][1] = (_Float16)Wh[(2 * k + 1) * H_DIM + col2];
        wB[k][0] = (_Float16)Wh[(2 * k) * H_DIM + col2 + 64];
        wB[k][1] = (_Float16)Wh[(2 * k + 1) * H_DIM + col2 + 64];
    }
    const float biasA = isS ? b1[col2] : 0.0f;
    const float biasB = isS ? b1[col2 + 64] : 0.0f;

    __syncthreads();

    // ---- ILP-4 over 16 rows; each b128 LDS read feeds 2 cols ----
    for (int r0 = rq * 16; r0 < rq * 16 + 16; r0 += 4) {
        const H2x4* e0 = (const H2x4*)&eT[(r0 + 0) * D_NODE];
        const H2x4* e1 = (const H2x4*)&eT[(r0 + 1) * D_NODE];
        const H2x4* e2 = (const H2x4*)&eT[(r0 + 2) * D_NODE];
        const H2x4* e3 = (const H2x4*)&eT[(r0 + 3) * D_NODE];
        float aA0 = biasA, aA1 = biasA, aA2 = biasA, aA3 = biasA;
        float aB0 = biasB, aB1 = biasB, aB2 = biasB, aB3 = biasB;
#pragma unroll
        for (int k8 = 0; k8 < D_NODE / 8; ++k8) {      // 8 iters
            const H2x4 v0 = e0[k8];
            const H2x4 v1 = e1[k8];
            const H2x4 v2 = e2[k8];
            const H2x4 v3 = e3[k8];
#pragma unroll
            for (int j = 0; j < 4; ++j) {
                const h2v wa = wA[4 * k8 + j];
                const h2v wb = wB[4 * k8 + j];
                aA0 = dot2acc(v0.h[j], wa, aA0); aB0 = dot2acc(v0.h[j], wb, aB0);
                aA1 = dot2acc(v1.h[j], wa, aA1); aB1 = dot2acc(v1.h[j], wb, aB1);
                aA2 = dot2acc(v2.h[j], wa, aA2); aB2 = dot2acc(v2.h[j], wb, aB2);
                aA3 = dot2acc(v3.h[j], wa, aA3); aB3 = dot2acc(v3.h[j], wb, aB3);
            }
        }
        const int row = rowBase + r0;
        if (row + 0 < rowsTot) {
            rec[(size_t)(row + 0) * REC_H + D_NODE + col2]      = __float2half(aA0);
            rec[(size_t)(row + 0) * REC_H + D_NODE + col2 + 64] = __float2half(aB0);
        }
        if (row + 1 < rowsTot) {
            rec[(size_t)(row + 1) * REC_H + D_NODE + col2]      = __float2half(aA1);
            rec[(size_t)(row + 1) * REC_H + D_NODE + col2 + 64] = __float2half(aB1);
        }
        if (row + 2 < rowsTot) {
            rec[(size_t)(row + 2) * REC_H + D_NODE + col2]      = __float2half(aA2);
            rec[(size_t)(row + 2) * REC_H + D_NODE + col2 + 64] = __float2half(aB2);
        }
        if (row + 3 < rowsTot) {
            rec[(size_t)(row + 3) * REC_H + D_NODE + col2]      = __float2half(aA3);
            rec[(size_t)(row + 3) * REC_H + D_NODE + col2 + 64] = __float2half(aB3);
        }
    }
}

// ---------------------------------------------------------------------------
// Main edge pass: 8 lanes/edge, 2 edges/thread, packed-f16 math.
//   cost = ||es-ea|| * sigmoid( dot(relu(P_s+P_a), W2) + b2 )
//   atomicAdd(segsum[s], exp(-cost/temp))   (no seg-max: vals in [-20,0])
// ---------------------------------------------------------------------------
__global__ void __launch_bounds__(256)
edge_main_kernel(const __half* __restrict__ recS,
                 const __half* __restrict__ recA,
                 const int* __restrict__ idx,
                 const float* __restrict__ W2,
                 const float* __restrict__ b2,
                 const float* __restrict__ logT,
                 float* __restrict__ out_costs,
                 float* __restrict__ segsum,
                 int E)
{
    const int gid = blockIdx.x * 256 + (int)threadIdx.x;
    const int p = gid >> 3;
    const int t = gid & 7;
    const int e0 = 2 * p;
    const int e1 = 2 * p + 1;
    if (e0 >= E) return;
    const bool has1 = (e1 < E);

    // paired index loads (e0,e1 adjacent; e0 even, E even -> 8B aligned)
    int s0, s1, a0, a1;
    {
        int2 sp = *(const int2*)(idx + e0);
        int2 ap = *(const int2*)(idx + E + e0);
        s0 = sp.x; s1 = has1 ? sp.y : sp.x;
        a0 = ap.x; a1 = has1 ? ap.y : ap.x;
    }

    const uint4* rs0 = (const uint4*)(recS + (size_t)s0 * REC_H);
    const uint4* ra0 = (const uint4*)(recA + (size_t)a0 * REC_H);
    const uint4* rs1 = (const uint4*)(recS + (size_t)s1 * REC_H);
    const uint4* ra1 = (const uint4*)(recA + (size_t)a1 * REC_H);

    // issue all 12 record loads (compiler keeps them in flight)
    uint4 es0 = rs0[t];          // e16 chunk t (8 halves)
    uint4 ea0 = ra0[t];
    uint4 p0s_lo = rs0[8 + t];   // P chunk t
    uint4 p0a_lo = ra0[8 + t];
    uint4 p0s_hi = rs0[16 + t];  // P chunk t+8
    uint4 p0a_hi = ra0[16 + t];
    uint4 es1 = rs1[t];
    uint4 ea1 = ra1[t];
    uint4 p1s_lo = rs1[8 + t];
    uint4 p1a_lo = ra1[8 + t];
    uint4 p1s_hi = rs1[16 + t];
    uint4 p1a_hi = ra1[16 + t];

    // W2 chunks t and t+8 as half2 (shared by both edges)
    __half2 wl[4], wh[4];
    {
        const float4* w4 = (const float4*)W2;
        const float4 l0 = w4[2 * t], l1 = w4[2 * t + 1];
        const float4 h0 = w4[2 * (t + 8)], h1 = w4[2 * (t + 8) + 1];
        wl[0] = __floats2half2_rn(l0.x, l0.y);
        wl[1] = __floats2half2_rn(l0.z, l0.w);
        wl[2] = __floats2half2_rn(l1.x, l1.y);
        wl[3] = __floats2half2_rn(l1.z, l1.w);
        wh[0] = __floats2half2_rn(h0.x, h0.y);
        wh[1] = __floats2half2_rn(h0.z, h0.w);
        wh[2] = __floats2half2_rn(h1.x, h1.y);
        wh[3] = __floats2half2_rn(h1.z, h1.w);
    }

    float n0 = 0.0f, g0 = 0.0f, n1 = 0.0f, g1 = 0.0f;

#define NORM_ACC(XS, XA, NACC)                                             \
    {                                                                      \
        const __half2* hs = (const __half2*)&XS;                           \
        const __half2* ha = (const __half2*)&XA;                           \
        _Pragma("unroll")                                                  \
        for (int k = 0; k < 4; ++k) {                                      \
            __half2 d = __hsub2(hs[k], ha[k]);                             \
            h2v dv = *(const h2v*)&d;                                      \
            NACC = dot2acc(dv, dv, NACC);                                  \
        }                                                                  \
    }

#define GATE_ACC(PS, PA, WARR, G)                                          \
    {                                                                      \
        const __half2* hp = (const __half2*)&PS;                           \
        const __half2* hq = (const __half2*)&PA;                           \
        _Pragma("unroll")                                                  \
        for (int k = 0; k < 4; ++k) {                                      \
            __half2 sm = relu2(__hadd2(hp[k], hq[k]));                     \
            G = dot2acc(*(const h2v*)&sm, *(const h2v*)&WARR[k], G);       \
        }                                                                  \
    }

    NORM_ACC(es0, ea0, n0)
    GATE_ACC(p0s_lo, p0a_lo, wl, g0)
    GATE_ACC(p0s_hi, p0a_hi, wh, g0)
    NORM_ACC(es1, ea1, n1)
    GATE_ACC(p1s_lo, p1a_lo, wl, g1)
    GATE_ACC(p1s_hi, p1a_hi, wh, g1)

    // --- 8-lane reductions ---
#pragma unroll
    for (int m = 1; m < 8; m <<= 1) {
        n0 += __shfl_xor(n0, m);
        g0 += __shfl_xor(g0, m);
        n1 += __shfl_xor(n1, m);
        g1 += __shfl_xor(g1, m);
    }

    if (t == 0) {
        const float invT = __expf(-logT[0]);
        const float bb = b2[0];
        {
            const float gate = 1.0f / (1.0f + __expf(-(g0 + bb)));
            const float cost = sqrtf(n0) * gate;
            out_costs[e0] = cost;
            atomicAdd(&segsum[s0], __expf(-cost * invT));
        }
        if (has1) {
            const float gate = 1.0f / (1.0f + __expf(-(g1 + bb)));
            const float cost = sqrtf(n1) * gate;
            out_costs[e1] = cost;
            atomicAdd(&segsum[s1], __expf(-cost * invT));
        }
    }
#undef NORM_ACC
#undef GATE_ACC
}

// ---------------------------------------------------------------------------
// edge_weights = exp(-cost/temp) / segsum[s]  (recompute ex from cost)
// ---------------------------------------------------------------------------
__global__ void __launch_bounds__(256)
edge_norm_kernel(const int* __restrict__ idx,
                 const float* __restrict__ out_costs,
                 const float* __restrict__ segsum,
                 const float* __restrict__ logT,
                 float* __restrict__ out_w,
                 int E)
{
    const int e = blockIdx.x * blockDim.x + threadIdx.x;
    if (e >= E) return;
    const int s = idx[e];
    const float invT = __expf(-logT[0]);
    const float ex = __expf(-out_costs[e] * invT);
    out_w[e] = ex / segsum[s];
}

// ---------------------------------------------------------------------------
extern "C" void kernel_launch(void* const* d_in, const int* in_sizes, int n_in,
                              void* d_out, int out_size, void* d_ws, size_t ws_size,
                              hipStream_t stream)
{
    const float* emb_s = (const float*)d_in[0];
    const float* emb_a = (const float*)d_in[1];
    const int*   idx   = (const int*)d_in[2];
    const float* W1    = (const float*)d_in[3];
    const float* b1    = (const float*)d_in[4];
    const float* W2    = (const float*)d_in[5];
    const float* b2    = (const float*)d_in[6];
    const float* logT  = (const float*)d_in[7];

    const int numS = in_sizes[0] / D_NODE;
    const int numA = in_sizes[1] / D_NODE;
    const int E    = in_sizes[2] / 2;

    float* out = (float*)d_out;            // [0,E) weights, [E,2E) costs

    // workspace layout (records 384 B, 16 B aligned)
    char* ws = (char*)d_ws;
    __half* recS   = (__half*)ws;   ws += (size_t)numS * REC_H * sizeof(__half);
    __half* recA   = (__half*)ws;   ws += (size_t)numA * REC_H * sizeof(__half);
    float*  segsum = (float*)ws;

    // fused prep: convert + P(f16, 2-col threads) + zero segsum
    const int pS = (numS + 63) / 64;
    const int pA = (numA + 63) / 64;
    const int zB = (numS + 255) / 256;
    prep_kernel<<<pS + pA + zB, 256, 0, stream>>>(emb_s, emb_a, W1, b1,
                                                  recS, recA, segsum,
                                                  numS, numA, pS, pA);

    // main edge pass (8 lanes/edge, 2 edges per lane-group)
    {
        const int pairs = (E + 1) / 2;
        const long long threads = (long long)pairs * 8;
        const int blocks = (int)((threads + 255) / 256);
        edge_main_kernel<<<blocks, 256, 0, stream>>>(recS, recA, idx, W2, b2,
                                                     logT, out + E, segsum, E);
    }

    edge_norm_kernel<<<(E + 255) / 256, 256, 0, stream>>>(idx, out + E, segsum,
                                                          logT, out, E);
}